// Round 1
// baseline (1552.052 us; speedup 1.0000x reference)
//
#include <hip/hip_runtime.h>
#include <hip/hip_bf16.h>
#include <cstdint>
#include <cstddef>

#define N_NODES 100000
#define N_EDGES 400000
#define IN_CH 1024
#define FEAT_CH 128
#define OUT_CH 3
#define NEG_SLOPE 0.01f

typedef __bf16 bf16x8 __attribute__((ext_vector_type(8)));
typedef unsigned short ushort8v __attribute__((ext_vector_type(8)));
typedef unsigned short ushort4v __attribute__((ext_vector_type(4)));
typedef float f32x4 __attribute__((ext_vector_type(4)));

__device__ __forceinline__ unsigned short f32_to_bf16_rne(float f) {
    uint32_t u = __float_as_uint(f);
    u += 0x7fffu + ((u >> 16) & 1u);
    return (unsigned short)(u >> 16);
}

// ---------------------------------------------------------------------------
// Convert W1_l / W1_r [1024,128] f32 -> transposed bf16 [128,1024]
// ---------------------------------------------------------------------------
__global__ void wt_kernel(const float* __restrict__ Wl, const float* __restrict__ Wr,
                          unsigned short* __restrict__ Wtl, unsigned short* __restrict__ Wtr)
{
    int idx = blockIdx.x * blockDim.x + threadIdx.x;
    if (idx >= IN_CH * FEAT_CH) return;
    int k = idx >> 7;        // / 128
    int c = idx & 127;
    Wtl[c * IN_CH + k] = f32_to_bf16_rne(Wl[idx]);
    Wtr[c * IN_CH + k] = f32_to_bf16_rne(Wr[idx]);
}

// ---------------------------------------------------------------------------
// GEMM: Y = X[100000,1024] @ W[1024,128]  (bf16 MFMA, fp32 accum)
// blockIdx.y = 0 -> W1_l -> Yl ; 1 -> W1_r -> Yr
// Block: 256 threads (4 waves 2x2), tile 128x128, BK=32.
// ---------------------------------------------------------------------------
__global__ __launch_bounds__(256) void gemm1(
    const float* __restrict__ X,
    const unsigned short* __restrict__ Wtl,
    const unsigned short* __restrict__ Wtr,
    float* __restrict__ Yl, float* __restrict__ Yr)
{
    constexpr int BK = 32;
    constexpr int LDSS = 40;  // 32 + 8 pad (16B-aligned rows, breaks pow2 stride)
    __shared__ unsigned short As[128 * LDSS];
    __shared__ unsigned short Bs[128 * LDSS];

    const int tid   = threadIdx.x;
    const int lane  = tid & 63;
    const int wave  = tid >> 6;
    const int waveM = wave >> 1;
    const int waveN = wave & 1;
    const int q     = lane >> 4;   // quad 0..3
    const int l16   = lane & 15;
    const int row0  = blockIdx.x * 128;

    const unsigned short* __restrict__ Wt = blockIdx.y ? Wtr : Wtl;
    float* __restrict__ Y = blockIdx.y ? Yr : Yl;

    f32x4 acc[4][4] = {};

    const int srow = tid >> 3;  // 0..31
    const int skv  = tid & 7;   // 0..7

    for (int kt = 0; kt < IN_CH / BK; ++kt) {
        const int k0 = kt * BK;
        // ---- stage A (fp32 -> bf16) and B (bf16 copy) ----
        #pragma unroll
        for (int r = 0; r < 4; ++r) {
            const int row  = srow + 32 * r;     // 0..127
            const int grow = row0 + row;
            float4 v = make_float4(0.f, 0.f, 0.f, 0.f);
            if (grow < N_NODES)
                v = *(const float4*)&X[(size_t)grow * IN_CH + k0 + skv * 4];
            ushort4v o;
            o.x = f32_to_bf16_rne(v.x); o.y = f32_to_bf16_rne(v.y);
            o.z = f32_to_bf16_rne(v.z); o.w = f32_to_bf16_rne(v.w);
            *(ushort4v*)&As[row * LDSS + skv * 4] = o;

            ushort4v b = *(const ushort4v*)&Wt[(size_t)row * IN_CH + k0 + skv * 4];
            *(ushort4v*)&Bs[row * LDSS + skv * 4] = b;
        }
        __syncthreads();

        // ---- fragments + MFMA ----
        bf16x8 af[4], bfr[4];
        #pragma unroll
        for (int mi = 0; mi < 4; ++mi) {
            const int m = waveM * 64 + mi * 16 + l16;
            af[mi] = __builtin_bit_cast(bf16x8, *(const ushort8v*)&As[m * LDSS + q * 8]);
        }
        #pragma unroll
        for (int ni = 0; ni < 4; ++ni) {
            const int n = waveN * 64 + ni * 16 + l16;
            bfr[ni] = __builtin_bit_cast(bf16x8, *(const ushort8v*)&Bs[n * LDSS + q * 8]);
        }
        #pragma unroll
        for (int mi = 0; mi < 4; ++mi)
            #pragma unroll
            for (int ni = 0; ni < 4; ++ni)
                acc[mi][ni] = __builtin_amdgcn_mfma_f32_16x16x32_bf16(
                    af[mi], bfr[ni], acc[mi][ni], 0, 0, 0);
        __syncthreads();
    }

    // ---- epilogue: C[row=q*4+r][col=l16] per 16x16 tile ----
    #pragma unroll
    for (int mi = 0; mi < 4; ++mi) {
        #pragma unroll
        for (int r = 0; r < 4; ++r) {
            const int grow = row0 + waveM * 64 + mi * 16 + q * 4 + r;
            if (grow < N_NODES) {
                #pragma unroll
                for (int ni = 0; ni < 4; ++ni) {
                    const int col = waveN * 64 + ni * 16 + l16;
                    Y[(size_t)grow * FEAT_CH + col] = acc[mi][ni][r];
                }
            }
        }
    }
}

// ---------------------------------------------------------------------------
// Edge scatter for layer 1: S[dst] += Yl[src] (128 ch), deg[dst] += 1
// 32 lanes per edge, float4 per lane.
// ---------------------------------------------------------------------------
__global__ void scatter1(const float* __restrict__ Yl,
                         const int* __restrict__ src, const int* __restrict__ dst,
                         float* __restrict__ S, float* __restrict__ deg)
{
    int gid = blockIdx.x * blockDim.x + threadIdx.x;
    int e = gid >> 5;
    if (e >= N_EDGES) return;
    int l = gid & 31;
    int sN = src[e], dN = dst[e];
    if (l == 0) unsafeAtomicAdd(&deg[dN], 1.0f);
    const float4 v = *(const float4*)&Yl[(size_t)sN * FEAT_CH + l * 4];
    float* p = &S[(size_t)dN * FEAT_CH + l * 4];
    unsafeAtomicAdd(p + 0, v.x);
    unsafeAtomicAdd(p + 1, v.y);
    unsafeAtomicAdd(p + 2, v.z);
    unsafeAtomicAdd(p + 3, v.w);
}

// ---------------------------------------------------------------------------
// h = leaky_relu(S/deg + Yr + b1)   (in-place into H buffer)
// ---------------------------------------------------------------------------
__global__ void combine1(float* __restrict__ H, const float* __restrict__ S,
                         const float* __restrict__ deg, const float* __restrict__ b1)
{
    int idx = blockIdx.x * blockDim.x + threadIdx.x;  // per float4 chunk
    if (idx >= N_NODES * (FEAT_CH / 4)) return;
    int node = idx >> 5;
    int cv = idx & 31;
    float invd = 1.0f / fmaxf(deg[node], 1.0f);
    float4 s = ((const float4*)S)[idx];
    float4 y = ((const float4*)H)[idx];
    float4 b = ((const float4*)b1)[cv];
    float4 h;
    h.x = fmaf(s.x, invd, y.x) + b.x;
    h.y = fmaf(s.y, invd, y.y) + b.y;
    h.z = fmaf(s.z, invd, y.z) + b.z;
    h.w = fmaf(s.w, invd, y.w) + b.w;
    h.x = h.x >= 0.f ? h.x : NEG_SLOPE * h.x;
    h.y = h.y >= 0.f ? h.y : NEG_SLOPE * h.y;
    h.z = h.z >= 0.f ? h.z : NEG_SLOPE * h.z;
    h.w = h.w >= 0.f ? h.w : NEG_SLOPE * h.w;
    ((float4*)H)[idx] = h;
}

// ---------------------------------------------------------------------------
// Layer-2 projections: Zl = h @ W2_l, Zr = h @ W2_r  (128 -> 3)
// one wave per node; lane covers k = 2*lane, 2*lane+1; shuffle-reduce.
// ---------------------------------------------------------------------------
__global__ void l2_kernel(const float* __restrict__ H,
                          const float* __restrict__ W2l, const float* __restrict__ W2r,
                          float* __restrict__ Zl, float* __restrict__ Zr)
{
    int gid = blockIdx.x * blockDim.x + threadIdx.x;
    int node = gid >> 6;
    int lane = threadIdx.x & 63;
    if (node >= N_NODES) return;
    float2 h = *(const float2*)&H[(size_t)node * FEAT_CH + lane * 2];
    const float* wl = &W2l[lane * 2 * 3];
    const float* wr = &W2r[lane * 2 * 3];
    float zl[3], zr[3];
    #pragma unroll
    for (int c = 0; c < 3; ++c) {
        zl[c] = h.x * wl[c] + h.y * wl[3 + c];
        zr[c] = h.x * wr[c] + h.y * wr[3 + c];
    }
    #pragma unroll
    for (int off = 32; off >= 1; off >>= 1) {
        #pragma unroll
        for (int c = 0; c < 3; ++c) {
            zl[c] += __shfl_xor(zl[c], off);
            zr[c] += __shfl_xor(zr[c], off);
        }
    }
    if (lane == 0) {
        #pragma unroll
        for (int c = 0; c < 3; ++c) {
            Zl[node * 3 + c] = zl[c];
            Zr[node * 3 + c] = zr[c];
        }
    }
}

// ---------------------------------------------------------------------------
// Edge scatter for layer 2: S2[dst] += Zl[src] (3 ch)
// ---------------------------------------------------------------------------
__global__ void scatter2(const float* __restrict__ Zl,
                         const int* __restrict__ src, const int* __restrict__ dst,
                         float* __restrict__ S2)
{
    int e = blockIdx.x * blockDim.x + threadIdx.x;
    if (e >= N_EDGES) return;
    int s = src[e], d = dst[e];
    #pragma unroll
    for (int c = 0; c < 3; ++c)
        unsafeAtomicAdd(&S2[d * 3 + c], Zl[s * 3 + c]);
}

// ---------------------------------------------------------------------------
// out = S2/deg + Zr + b2
// ---------------------------------------------------------------------------
__global__ void final_kernel(const float* __restrict__ S2, const float* __restrict__ Zr,
                             const float* __restrict__ deg, const float* __restrict__ b2,
                             float* __restrict__ out)
{
    int idx = blockIdx.x * blockDim.x + threadIdx.x;
    if (idx >= N_NODES * OUT_CH) return;
    int node = idx / 3;
    int c = idx - node * 3;
    out[idx] = S2[idx] / fmaxf(deg[node], 1.0f) + Zr[idx] + b2[c];
}

// ---------------------------------------------------------------------------
extern "C" void kernel_launch(void* const* d_in, const int* in_sizes, int n_in,
                              void* d_out, int out_size, void* d_ws, size_t ws_size,
                              hipStream_t stream)
{
    const float* X   = (const float*)d_in[0];
    const int*   e2  = (const int*)d_in[2];     // edges2 [2, E] int32
    const float* W1l = (const float*)d_in[5];
    const float* W1r = (const float*)d_in[6];
    const float* b1  = (const float*)d_in[7];
    const float* W2l = (const float*)d_in[8];
    const float* W2r = (const float*)d_in[9];
    const float* b2  = (const float*)d_in[10];
    const int* src = e2;
    const int* dst = e2 + N_EDGES;

    char* ws = (char*)d_ws;
    size_t off = 0;
    auto alloc = [&](size_t bytes) -> void* {
        void* p = ws + off;
        off += (bytes + 255) & ~(size_t)255;
        return p;
    };
    const size_t NB = (size_t)N_NODES * FEAT_CH * sizeof(float);  // 51.2 MB
    float* Yl  = (float*)alloc(NB);
    float* H   = (float*)alloc(NB);                       // Yr, then h (in place)
    float* S   = (float*)alloc(NB);
    float* deg = (float*)alloc((size_t)N_NODES * sizeof(float));
    float* Zl  = (float*)alloc((size_t)N_NODES * OUT_CH * sizeof(float));
    float* Zr  = (float*)alloc((size_t)N_NODES * OUT_CH * sizeof(float));
    float* S2  = (float*)alloc((size_t)N_NODES * OUT_CH * sizeof(float));
    unsigned short* Wtl = (unsigned short*)alloc((size_t)IN_CH * FEAT_CH * 2);
    unsigned short* Wtr = (unsigned short*)alloc((size_t)IN_CH * FEAT_CH * 2);

    // zero accumulators (ws is poisoned 0xAA before every timed call)
    hipMemsetAsync(S,   0, NB, stream);
    hipMemsetAsync(deg, 0, (size_t)N_NODES * sizeof(float), stream);
    hipMemsetAsync(S2,  0, (size_t)N_NODES * OUT_CH * sizeof(float), stream);

    wt_kernel<<<(IN_CH * FEAT_CH + 255) / 256, 256, 0, stream>>>(W1l, W1r, Wtl, Wtr);

    dim3 g1((N_NODES + 127) / 128, 2);
    gemm1<<<g1, 256, 0, stream>>>(X, Wtl, Wtr, Yl, H);

    scatter1<<<(N_EDGES * 32 + 255) / 256, 256, 0, stream>>>(Yl, src, dst, S, deg);

    combine1<<<(N_NODES * (FEAT_CH / 4) + 255) / 256, 256, 0, stream>>>(H, S, deg, b1);

    l2_kernel<<<(N_NODES * 64 + 255) / 256, 256, 0, stream>>>(H, W2l, W2r, Zl, Zr);

    scatter2<<<(N_EDGES + 255) / 256, 256, 0, stream>>>(Zl, src, dst, S2);

    final_kernel<<<(N_NODES * OUT_CH + 255) / 256, 256, 0, stream>>>(S2, Zr, deg, b2,
                                                                     (float*)d_out);
}

// Round 2
// 1014.964 us; speedup vs baseline: 1.5292x; 1.5292x over previous
//
#include <hip/hip_runtime.h>
#include <hip/hip_bf16.h>
#include <cstdint>
#include <cstddef>

#define N_NODES 100000
#define N_EDGES 400000
#define IN_CH 1024
#define FEAT_CH 128
#define OUT_CH 3
#define NEG_SLOPE 0.01f

typedef __bf16 bf16x8 __attribute__((ext_vector_type(8)));
typedef unsigned short ushort8v __attribute__((ext_vector_type(8)));
typedef unsigned short ushort4v __attribute__((ext_vector_type(4)));
typedef float f32x4 __attribute__((ext_vector_type(4)));

__device__ __forceinline__ unsigned short f32_to_bf16_rne(float f) {
    uint32_t u = __float_as_uint(f);
    u += 0x7fffu + ((u >> 16) & 1u);
    return (unsigned short)(u >> 16);
}

// ---------------------------------------------------------------------------
// Convert W1_l / W1_r [1024,128] f32 -> transposed bf16 [128,1024]
// ---------------------------------------------------------------------------
__global__ void wt_kernel(const float* __restrict__ Wl, const float* __restrict__ Wr,
                          unsigned short* __restrict__ Wtl, unsigned short* __restrict__ Wtr)
{
    int idx = blockIdx.x * blockDim.x + threadIdx.x;
    if (idx >= IN_CH * FEAT_CH) return;
    int k = idx >> 7;        // / 128
    int c = idx & 127;
    Wtl[c * IN_CH + k] = f32_to_bf16_rne(Wl[idx]);
    Wtr[c * IN_CH + k] = f32_to_bf16_rne(Wr[idx]);
}

// ---------------------------------------------------------------------------
// Counting-sort step 1: histogram of dst
// ---------------------------------------------------------------------------
__global__ void hist_kernel(const int* __restrict__ dst, int* __restrict__ cnt)
{
    int e = blockIdx.x * blockDim.x + threadIdx.x;
    if (e >= N_EDGES) return;
    atomicAdd(&cnt[dst[e]], 1);
}

// ---------------------------------------------------------------------------
// Counting-sort step 2: exclusive scan over cnt[100000] -> rowptr[100001]
// Single block of 1024 threads, each handles a contiguous chunk.
// ---------------------------------------------------------------------------
__global__ __launch_bounds__(1024) void scan_kernel(const int* __restrict__ cnt,
                                                    int* __restrict__ rowptr)
{
    __shared__ int sums[1024];
    const int t = threadIdx.x;
    const int CH = (N_NODES + 1023) / 1024;  // 98
    const int start = t * CH;
    const int end = min(start + CH, N_NODES);
    int s = 0;
    for (int i = start; i < end; ++i) s += cnt[i];
    sums[t] = s;
    __syncthreads();
    // Hillis-Steele inclusive scan in LDS
    for (int off = 1; off < 1024; off <<= 1) {
        int tmp = (t >= off) ? sums[t - off] : 0;
        __syncthreads();
        if (t >= off) sums[t] += tmp;
        __syncthreads();
    }
    int run = sums[t] - s;  // exclusive prefix of this chunk
    for (int i = start; i < end; ++i) { rowptr[i] = run; run += cnt[i]; }
    if (t == 1023) rowptr[N_NODES] = N_EDGES;
}

// ---------------------------------------------------------------------------
// Counting-sort step 3: place src into dst-sorted order
// ---------------------------------------------------------------------------
__global__ void scatter_edges(const int* __restrict__ src, const int* __restrict__ dst,
                              const int* __restrict__ rowptr, int* __restrict__ cursor,
                              int* __restrict__ sorted_src)
{
    int e = blockIdx.x * blockDim.x + threadIdx.x;
    if (e >= N_EDGES) return;
    int d = dst[e];
    int pos = rowptr[d] + atomicAdd(&cursor[d], 1);
    sorted_src[pos] = src[e];
}

// ---------------------------------------------------------------------------
// GEMM: Y = X[100000,1024] @ W[1024,128]  (bf16 MFMA, fp32 accum)
// blockIdx.y = 0 -> W1_l -> Yl ; 1 -> W1_r -> Yr
// ---------------------------------------------------------------------------
__global__ __launch_bounds__(256) void gemm1(
    const float* __restrict__ X,
    const unsigned short* __restrict__ Wtl,
    const unsigned short* __restrict__ Wtr,
    float* __restrict__ Yl, float* __restrict__ Yr)
{
    constexpr int BK = 32;
    constexpr int LDSS = 40;  // 32 + 8 pad
    __shared__ unsigned short As[128 * LDSS];
    __shared__ unsigned short Bs[128 * LDSS];

    const int tid   = threadIdx.x;
    const int lane  = tid & 63;
    const int wave  = tid >> 6;
    const int waveM = wave >> 1;
    const int waveN = wave & 1;
    const int q     = lane >> 4;
    const int l16   = lane & 15;
    const int row0  = blockIdx.x * 128;

    const unsigned short* __restrict__ Wt = blockIdx.y ? Wtr : Wtl;
    float* __restrict__ Y = blockIdx.y ? Yr : Yl;

    f32x4 acc[4][4] = {};

    const int srow = tid >> 3;
    const int skv  = tid & 7;

    for (int kt = 0; kt < IN_CH / BK; ++kt) {
        const int k0 = kt * BK;
        #pragma unroll
        for (int r = 0; r < 4; ++r) {
            const int row  = srow + 32 * r;
            const int grow = row0 + row;
            float4 v = make_float4(0.f, 0.f, 0.f, 0.f);
            if (grow < N_NODES)
                v = *(const float4*)&X[(size_t)grow * IN_CH + k0 + skv * 4];
            ushort4v o;
            o.x = f32_to_bf16_rne(v.x); o.y = f32_to_bf16_rne(v.y);
            o.z = f32_to_bf16_rne(v.z); o.w = f32_to_bf16_rne(v.w);
            *(ushort4v*)&As[row * LDSS + skv * 4] = o;

            ushort4v b = *(const ushort4v*)&Wt[(size_t)row * IN_CH + k0 + skv * 4];
            *(ushort4v*)&Bs[row * LDSS + skv * 4] = b;
        }
        __syncthreads();

        bf16x8 af[4], bfr[4];
        #pragma unroll
        for (int mi = 0; mi < 4; ++mi) {
            const int m = waveM * 64 + mi * 16 + l16;
            af[mi] = __builtin_bit_cast(bf16x8, *(const ushort8v*)&As[m * LDSS + q * 8]);
        }
        #pragma unroll
        for (int ni = 0; ni < 4; ++ni) {
            const int n = waveN * 64 + ni * 16 + l16;
            bfr[ni] = __builtin_bit_cast(bf16x8, *(const ushort8v*)&Bs[n * LDSS + q * 8]);
        }
        #pragma unroll
        for (int mi = 0; mi < 4; ++mi)
            #pragma unroll
            for (int ni = 0; ni < 4; ++ni)
                acc[mi][ni] = __builtin_amdgcn_mfma_f32_16x16x32_bf16(
                    af[mi], bfr[ni], acc[mi][ni], 0, 0, 0);
        __syncthreads();
    }

    #pragma unroll
    for (int mi = 0; mi < 4; ++mi) {
        #pragma unroll
        for (int r = 0; r < 4; ++r) {
            const int grow = row0 + waveM * 64 + mi * 16 + q * 4 + r;
            if (grow < N_NODES) {
                #pragma unroll
                for (int ni = 0; ni < 4; ++ni) {
                    const int col = waveN * 64 + ni * 16 + l16;
                    Y[(size_t)grow * FEAT_CH + col] = acc[mi][ni][r];
                }
            }
        }
    }
}

// ---------------------------------------------------------------------------
// Layer-1 aggregation (gather, no atomics) fused with combine:
// H[n] = leaky_relu( (sum_{e in CSR[n]} Yl[sorted_src[e]]) / max(deg,1)
//                    + Yr[n] + b1 )
// 32 lanes per node, float4 per lane.
// ---------------------------------------------------------------------------
__global__ void agg1(const float* __restrict__ Yl,
                     const int* __restrict__ rowptr, const int* __restrict__ sorted_src,
                     float* __restrict__ H /* in: Yr, out: h */,
                     const float* __restrict__ b1)
{
    int gid = blockIdx.x * blockDim.x + threadIdx.x;
    int node = gid >> 5;
    if (node >= N_NODES) return;
    int l = gid & 31;

    int beg = rowptr[node];
    int end = rowptr[node + 1];
    float4 acc = make_float4(0.f, 0.f, 0.f, 0.f);
    for (int e = beg; e < end; ++e) {
        int s = sorted_src[e];  // broadcast across the 32-lane group
        const float4 v = *(const float4*)&Yl[(size_t)s * FEAT_CH + l * 4];
        acc.x += v.x; acc.y += v.y; acc.z += v.z; acc.w += v.w;
    }
    float invd = 1.0f / fmaxf((float)(end - beg), 1.0f);
    float4 y = *(const float4*)&H[(size_t)node * FEAT_CH + l * 4];
    float4 b = ((const float4*)b1)[l];
    float4 h;
    h.x = fmaf(acc.x, invd, y.x) + b.x;
    h.y = fmaf(acc.y, invd, y.y) + b.y;
    h.z = fmaf(acc.z, invd, y.z) + b.z;
    h.w = fmaf(acc.w, invd, y.w) + b.w;
    h.x = h.x >= 0.f ? h.x : NEG_SLOPE * h.x;
    h.y = h.y >= 0.f ? h.y : NEG_SLOPE * h.y;
    h.z = h.z >= 0.f ? h.z : NEG_SLOPE * h.z;
    h.w = h.w >= 0.f ? h.w : NEG_SLOPE * h.w;
    *(float4*)&H[(size_t)node * FEAT_CH + l * 4] = h;
}

// ---------------------------------------------------------------------------
// Layer-2 projections: Zl = h @ W2_l, Zr = h @ W2_r  (128 -> 3)
// one wave per node; lane covers k = 2*lane, 2*lane+1; shuffle-reduce.
// ---------------------------------------------------------------------------
__global__ void l2_kernel(const float* __restrict__ H,
                          const float* __restrict__ W2l, const float* __restrict__ W2r,
                          float* __restrict__ Zl, float* __restrict__ Zr)
{
    int gid = blockIdx.x * blockDim.x + threadIdx.x;
    int node = gid >> 6;
    int lane = threadIdx.x & 63;
    if (node >= N_NODES) return;
    float2 h = *(const float2*)&H[(size_t)node * FEAT_CH + lane * 2];
    const float* wl = &W2l[lane * 2 * 3];
    const float* wr = &W2r[lane * 2 * 3];
    float zl[3], zr[3];
    #pragma unroll
    for (int c = 0; c < 3; ++c) {
        zl[c] = h.x * wl[c] + h.y * wl[3 + c];
        zr[c] = h.x * wr[c] + h.y * wr[3 + c];
    }
    #pragma unroll
    for (int off = 32; off >= 1; off >>= 1) {
        #pragma unroll
        for (int c = 0; c < 3; ++c) {
            zl[c] += __shfl_xor(zl[c], off);
            zr[c] += __shfl_xor(zr[c], off);
        }
    }
    if (lane == 0) {
        #pragma unroll
        for (int c = 0; c < 3; ++c) {
            Zl[node * 3 + c] = zl[c];
            Zr[node * 3 + c] = zr[c];
        }
    }
}

// ---------------------------------------------------------------------------
// Layer-2 aggregation (gather) fused with final combine:
// out[n,c] = (sum Zl[src,c]) / max(deg,1) + Zr[n,c] + b2[c]
// 4 threads per node (c = 0..2 active).
// ---------------------------------------------------------------------------
__global__ void agg2_final(const float* __restrict__ Zl, const float* __restrict__ Zr,
                           const int* __restrict__ rowptr, const int* __restrict__ sorted_src,
                           const float* __restrict__ b2, float* __restrict__ out)
{
    int gid = blockIdx.x * blockDim.x + threadIdx.x;
    int node = gid >> 2;
    int c = gid & 3;
    if (node >= N_NODES || c >= OUT_CH) return;
    int beg = rowptr[node];
    int end = rowptr[node + 1];
    float acc = 0.f;
    for (int e = beg; e < end; ++e) {
        int s = sorted_src[e];
        acc += Zl[s * 3 + c];
    }
    float invd = 1.0f / fmaxf((float)(end - beg), 1.0f);
    out[node * 3 + c] = fmaf(acc, invd, Zr[node * 3 + c]) + b2[c];
}

// ---------------------------------------------------------------------------
extern "C" void kernel_launch(void* const* d_in, const int* in_sizes, int n_in,
                              void* d_out, int out_size, void* d_ws, size_t ws_size,
                              hipStream_t stream)
{
    const float* X   = (const float*)d_in[0];
    const int*   e2  = (const int*)d_in[2];     // edges2 [2, E] int32
    const float* W1l = (const float*)d_in[5];
    const float* W1r = (const float*)d_in[6];
    const float* b1  = (const float*)d_in[7];
    const float* W2l = (const float*)d_in[8];
    const float* W2r = (const float*)d_in[9];
    const float* b2  = (const float*)d_in[10];
    const int* src = e2;
    const int* dst = e2 + N_EDGES;

    char* ws = (char*)d_ws;
    size_t off = 0;
    auto alloc = [&](size_t bytes) -> void* {
        void* p = ws + off;
        off += (bytes + 255) & ~(size_t)255;
        return p;
    };
    const size_t NB = (size_t)N_NODES * FEAT_CH * sizeof(float);  // 51.2 MB
    float* Yl  = (float*)alloc(NB);
    float* H   = (float*)alloc(NB);   // Yr, then h (in place)
    float* Zl  = (float*)alloc((size_t)N_NODES * OUT_CH * sizeof(float));
    float* Zr  = (float*)alloc((size_t)N_NODES * OUT_CH * sizeof(float));
    unsigned short* Wtl = (unsigned short*)alloc((size_t)IN_CH * FEAT_CH * 2);
    unsigned short* Wtr = (unsigned short*)alloc((size_t)IN_CH * FEAT_CH * 2);
    int* cnt        = (int*)alloc((size_t)N_NODES * sizeof(int));
    int* cursor     = (int*)alloc((size_t)N_NODES * sizeof(int));
    int* rowptr     = (int*)alloc((size_t)(N_NODES + 1) * sizeof(int));
    int* sorted_src = (int*)alloc((size_t)N_EDGES * sizeof(int));

    hipMemsetAsync(cnt,    0, (size_t)N_NODES * sizeof(int), stream);
    hipMemsetAsync(cursor, 0, (size_t)N_NODES * sizeof(int), stream);

    // --- build dst-sorted CSR (counting sort) ---
    hist_kernel<<<(N_EDGES + 255) / 256, 256, 0, stream>>>(dst, cnt);
    scan_kernel<<<1, 1024, 0, stream>>>(cnt, rowptr);
    scatter_edges<<<(N_EDGES + 255) / 256, 256, 0, stream>>>(src, dst, rowptr, cursor,
                                                             sorted_src);

    // --- layer 1 ---
    wt_kernel<<<(IN_CH * FEAT_CH + 255) / 256, 256, 0, stream>>>(W1l, W1r, Wtl, Wtr);
    dim3 g1((N_NODES + 127) / 128, 2);
    gemm1<<<g1, 256, 0, stream>>>(X, Wtl, Wtr, Yl, H);
    agg1<<<(N_NODES * 32 + 255) / 256, 256, 0, stream>>>(Yl, rowptr, sorted_src, H, b1);

    // --- layer 2 ---
    l2_kernel<<<(N_NODES * 64 + 255) / 256, 256, 0, stream>>>(H, W2l, W2r, Zl, Zr);
    agg2_final<<<(N_NODES * 4 + 255) / 256, 256, 0, stream>>>(Zl, Zr, rowptr, sorted_src,
                                                              b2, (float*)d_out);
}

// Round 3
// 743.247 us; speedup vs baseline: 2.0882x; 1.3656x over previous
//
#include <hip/hip_runtime.h>
#include <hip/hip_bf16.h>
#include <cstdint>
#include <cstddef>

#define N_NODES 100000
#define N_EDGES 400000
#define IN_CH 1024
#define FEAT_CH 128
#define OUT_CH 3
#define NEG_SLOPE 0.01f
#define NCHUNK 196  // ceil(100000 / 512)

typedef __bf16 bf16x8 __attribute__((ext_vector_type(8)));
typedef unsigned short ushort8v __attribute__((ext_vector_type(8)));
typedef float f32x4 __attribute__((ext_vector_type(4)));

__device__ __forceinline__ unsigned short f32_to_bf16_rne(float f) {
    uint32_t u = __float_as_uint(f);
    u += 0x7fffu + ((u >> 16) & 1u);
    return (unsigned short)(u >> 16);
}

typedef const __attribute__((address_space(1))) unsigned char ga_t;
typedef __attribute__((address_space(3))) unsigned char la_t;
__device__ __forceinline__ void glds16(const void* g, void* l) {
    __builtin_amdgcn_global_load_lds((ga_t*)g, (la_t*)l, 16, 0, 0);
}

// ---------------------------------------------------------------------------
// Wcat[n][k] = bf16( n<128 ? W1_l[k][n] : W1_r[k][n-128] )   [256,1024]
// ---------------------------------------------------------------------------
__global__ void wt_kernel(const float* __restrict__ Wl, const float* __restrict__ Wr,
                          unsigned short* __restrict__ Wcat)
{
    int idx = blockIdx.x * blockDim.x + threadIdx.x;
    if (idx >= 256 * IN_CH) return;
    int n = idx >> 10;
    int k = idx & 1023;
    float v = (n < FEAT_CH) ? Wl[k * FEAT_CH + n] : Wr[k * FEAT_CH + (n - FEAT_CH)];
    Wcat[idx] = f32_to_bf16_rne(v);
}

// ---------------------------------------------------------------------------
// CSR build: histogram of dst
// ---------------------------------------------------------------------------
__global__ void hist_kernel(const int* __restrict__ dst, int* __restrict__ cnt)
{
    int e = blockIdx.x * blockDim.x + threadIdx.x;
    if (e >= N_EDGES) return;
    atomicAdd(&cnt[dst[e]], 1);
}

// ---------------------------------------------------------------------------
// Parallel exclusive scan, phase 1: per-chunk (512 elems) exclusive scan
// ---------------------------------------------------------------------------
__global__ __launch_bounds__(256) void scan_p1(const int* __restrict__ cnt,
                                               int* __restrict__ rowptr,
                                               int* __restrict__ bsum)
{
    __shared__ int sdata[256];
    const int t = threadIdx.x;
    const int c0 = blockIdx.x * 512;
    const int i0 = c0 + 2 * t;
    int v0 = (i0     < N_NODES) ? cnt[i0]     : 0;
    int v1 = (i0 + 1 < N_NODES) ? cnt[i0 + 1] : 0;
    int s = v0 + v1;
    sdata[t] = s;
    __syncthreads();
    #pragma unroll
    for (int off = 1; off < 256; off <<= 1) {
        int tmp = (t >= off) ? sdata[t - off] : 0;
        __syncthreads();
        sdata[t] += tmp;
        __syncthreads();
    }
    int ex = sdata[t] - s;  // exclusive prefix within chunk
    if (i0     < N_NODES) rowptr[i0]     = ex;
    if (i0 + 1 < N_NODES) rowptr[i0 + 1] = ex + v0;
    if (t == 255) bsum[blockIdx.x] = sdata[255];
}

// phase 2: exclusive scan of 196 block sums (single block)
__global__ __launch_bounds__(256) void scan_p2(const int* __restrict__ bsum,
                                               int* __restrict__ boff)
{
    __shared__ int sdata[256];
    const int t = threadIdx.x;
    int v = (t < NCHUNK) ? bsum[t] : 0;
    sdata[t] = v;
    __syncthreads();
    #pragma unroll
    for (int off = 1; off < 256; off <<= 1) {
        int tmp = (t >= off) ? sdata[t - off] : 0;
        __syncthreads();
        sdata[t] += tmp;
        __syncthreads();
    }
    if (t < NCHUNK) boff[t] = sdata[t] - v;
}

// phase 3: add chunk offsets
__global__ void scan_p3(int* __restrict__ rowptr, const int* __restrict__ boff)
{
    const int c0 = blockIdx.x * 512;
    const int add = boff[blockIdx.x];
    const int t = threadIdx.x;
    int i0 = c0 + 2 * t;
    if (i0     < N_NODES) rowptr[i0]     += add;
    if (i0 + 1 < N_NODES) rowptr[i0 + 1] += add;
    if (blockIdx.x == 0 && t == 0) rowptr[N_NODES] = N_EDGES;
}

// ---------------------------------------------------------------------------
// CSR build: place src into dst-sorted order
// ---------------------------------------------------------------------------
__global__ void scatter_edges(const int* __restrict__ src, const int* __restrict__ dst,
                              const int* __restrict__ rowptr, int* __restrict__ cursor,
                              int* __restrict__ sorted_src)
{
    int e = blockIdx.x * blockDim.x + threadIdx.x;
    if (e >= N_EDGES) return;
    int d = dst[e];
    int pos = rowptr[d] + atomicAdd(&cursor[d], 1);
    sorted_src[pos] = src[e];
}

// ---------------------------------------------------------------------------
// Fused GEMM: [Yl | Yr] = X[100000,1024] @ [W1_l | W1_r]   (bf16 MFMA)
// Tile 128 rows x 256 cols, BK=64, 256 threads (4 waves, 2x2).
// A: fp32 -> register prefetch -> bf16 convert -> XOR-swizzled LDS.
// B: bf16 Wcat via global_load_lds width=16 (unpadded layout).
// ---------------------------------------------------------------------------
__global__ __launch_bounds__(256, 2) void gemm_fused(
    const float* __restrict__ X, const unsigned short* __restrict__ Wcat,
    float* __restrict__ Yl, float* __restrict__ Yr)
{
    __shared__ unsigned short As[128 * 64];  // [row][chunk^(row&7)] chunks of 8 bf16
    __shared__ unsigned short Bs[256 * 64];  // [n][k] unpadded (glds layout)

    const int tid   = threadIdx.x;
    const int lane  = tid & 63;
    const int wave  = tid >> 6;
    const int waveM = wave >> 1;
    const int waveN = wave & 1;
    const int q     = lane >> 4;
    const int l16   = lane & 15;
    const int esw   = l16 & 7;         // read-side swizzle key
    const int row0  = blockIdx.x * 128;

    const int arow = tid >> 3;          // 0..31 (+32p)
    const int au   = tid & 7;           // A chunk
    const int aesw = arow & 7;          // write-side swizzle key

    f32x4 acc[4][8] = {};
    float4 pre[8];

    auto prefetchA = [&](int k0) {
        #pragma unroll
        for (int p = 0; p < 4; ++p) {
            const int grow = row0 + p * 32 + arow;
            const float* gp = &X[(size_t)grow * IN_CH + k0 + au * 8];
            if (grow < N_NODES) {
                pre[2 * p]     = *(const float4*)gp;
                pre[2 * p + 1] = *(const float4*)(gp + 4);
            } else {
                pre[2 * p]     = make_float4(0.f, 0.f, 0.f, 0.f);
                pre[2 * p + 1] = make_float4(0.f, 0.f, 0.f, 0.f);
            }
        }
    };

    prefetchA(0);

    for (int kt = 0; kt < IN_CH / 64; ++kt) {
        const int k0 = kt * 64;

        // ---- B: async global->LDS, 8 issues/wave, 8 rows (1 KB) per issue ----
        #pragma unroll
        for (int i = 0; i < 8; ++i) {
            const int gi = wave * 8 + i;                   // 0..31
            const int r  = gi * 8 + (lane >> 3);
            glds16(&Wcat[(size_t)r * IN_CH + k0 + (lane & 7) * 8],
                   &Bs[gi * 8 * 64]);
        }

        // ---- A: convert prefetched regs, swizzled LDS write ----
        #pragma unroll
        for (int p = 0; p < 4; ++p) {
            const int row = p * 32 + arow;
            const int c   = au ^ aesw;
            const float4 a = pre[2 * p], b = pre[2 * p + 1];
            ushort8v o;
            o[0] = f32_to_bf16_rne(a.x); o[1] = f32_to_bf16_rne(a.y);
            o[2] = f32_to_bf16_rne(a.z); o[3] = f32_to_bf16_rne(a.w);
            o[4] = f32_to_bf16_rne(b.x); o[5] = f32_to_bf16_rne(b.y);
            o[6] = f32_to_bf16_rne(b.z); o[7] = f32_to_bf16_rne(b.w);
            *(ushort8v*)&As[row * 64 + c * 8] = o;
        }

        if (kt + 1 < IN_CH / 64) prefetchA(k0 + 64);

        __syncthreads();

        // ---- MFMA: 2 k-steps of 32, 4x8 tiles per wave ----
        #pragma unroll
        for (int s = 0; s < 2; ++s) {
            bf16x8 af[4], bfr[8];
            const int kc = q + 4 * s;   // chunk index 0..7
            #pragma unroll
            for (int mi = 0; mi < 4; ++mi) {
                const int m = waveM * 64 + mi * 16 + l16;
                af[mi] = __builtin_bit_cast(
                    bf16x8, *(const ushort8v*)&As[m * 64 + (kc ^ esw) * 8]);
            }
            #pragma unroll
            for (int ni = 0; ni < 8; ++ni) {
                const int n = waveN * 128 + ni * 16 + l16;
                bfr[ni] = __builtin_bit_cast(
                    bf16x8, *(const ushort8v*)&Bs[n * 64 + kc * 8]);
            }
            #pragma unroll
            for (int mi = 0; mi < 4; ++mi)
                #pragma unroll
                for (int ni = 0; ni < 8; ++ni)
                    acc[mi][ni] = __builtin_amdgcn_mfma_f32_16x16x32_bf16(
                        af[mi], bfr[ni], acc[mi][ni], 0, 0, 0);
        }
        __syncthreads();
    }

    // ---- epilogue: waveN=0 -> Yl, waveN=1 -> Yr ----
    float* __restrict__ Ybuf = waveN ? Yr : Yl;
    #pragma unroll
    for (int mi = 0; mi < 4; ++mi) {
        #pragma unroll
        for (int r = 0; r < 4; ++r) {
            const int grow = row0 + waveM * 64 + mi * 16 + q * 4 + r;
            if (grow < N_NODES) {
                #pragma unroll
                for (int ni = 0; ni < 8; ++ni)
                    Ybuf[(size_t)grow * FEAT_CH + ni * 16 + l16] = acc[mi][ni][r];
            }
        }
    }
}

// ---------------------------------------------------------------------------
// Fused layer-1 aggregation + combine + layer-2 projection.
// One wave per node; lane holds channels 2l, 2l+1.
// h = leaky( (sum Yl[src]) / max(deg,1) + Yr[node] + b1 )  (in registers)
// Zl = h @ W2_l, Zr = h @ W2_r  via shuffle reduction.
// ---------------------------------------------------------------------------
__global__ __launch_bounds__(256) void fused_agg(
    const float* __restrict__ Yl, const float* __restrict__ Yr,
    const int* __restrict__ rowptr, const int* __restrict__ sorted_src,
    const float* __restrict__ b1,
    const float* __restrict__ W2l, const float* __restrict__ W2r,
    float* __restrict__ Zl, float* __restrict__ Zr)
{
    int gid = blockIdx.x * blockDim.x + threadIdx.x;
    int node = gid >> 6;
    if (node >= N_NODES) return;
    int lane = threadIdx.x & 63;

    int beg = rowptr[node], end = rowptr[node + 1];
    float ax = 0.f, ay = 0.f;
    for (int e = beg; e < end; ++e) {
        int s = sorted_src[e];
        float2 v = *(const float2*)&Yl[(size_t)s * FEAT_CH + lane * 2];
        ax += v.x; ay += v.y;
    }
    float invd = 1.0f / fmaxf((float)(end - beg), 1.0f);
    float2 y  = *(const float2*)&Yr[(size_t)node * FEAT_CH + lane * 2];
    float2 bb = *(const float2*)&b1[lane * 2];
    float hx = fmaf(ax, invd, y.x) + bb.x;
    float hy = fmaf(ay, invd, y.y) + bb.y;
    hx = hx >= 0.f ? hx : NEG_SLOPE * hx;
    hy = hy >= 0.f ? hy : NEG_SLOPE * hy;

    const float* wl = &W2l[lane * 2 * 3];
    const float* wr = &W2r[lane * 2 * 3];
    float z[6];
    #pragma unroll
    for (int c = 0; c < 3; ++c) {
        z[c]     = hx * wl[c] + hy * wl[3 + c];
        z[3 + c] = hx * wr[c] + hy * wr[3 + c];
    }
    #pragma unroll
    for (int off = 32; off >= 1; off >>= 1)
        #pragma unroll
        for (int c = 0; c < 6; ++c)
            z[c] += __shfl_xor(z[c], off);

    if (lane == 0) {
        Zl[node * 3 + 0] = z[0]; Zl[node * 3 + 1] = z[1]; Zl[node * 3 + 2] = z[2];
        Zr[node * 3 + 0] = z[3]; Zr[node * 3 + 1] = z[4]; Zr[node * 3 + 2] = z[5];
    }
}

// ---------------------------------------------------------------------------
// Layer-2 aggregation (gather) + final combine:
// out[n,c] = (sum Zl[src,c]) / max(deg,1) + Zr[n,c] + b2[c]
// ---------------------------------------------------------------------------
__global__ void agg2_final(const float* __restrict__ Zl, const float* __restrict__ Zr,
                           const int* __restrict__ rowptr, const int* __restrict__ sorted_src,
                           const float* __restrict__ b2, float* __restrict__ out)
{
    int gid = blockIdx.x * blockDim.x + threadIdx.x;
    int node = gid >> 2;
    int c = gid & 3;
    if (node >= N_NODES || c >= OUT_CH) return;
    int beg = rowptr[node], end = rowptr[node + 1];
    float acc = 0.f;
    for (int e = beg; e < end; ++e)
        acc += Zl[sorted_src[e] * 3 + c];
    float invd = 1.0f / fmaxf((float)(end - beg), 1.0f);
    out[node * 3 + c] = fmaf(acc, invd, Zr[node * 3 + c]) + b2[c];
}

// ---------------------------------------------------------------------------
extern "C" void kernel_launch(void* const* d_in, const int* in_sizes, int n_in,
                              void* d_out, int out_size, void* d_ws, size_t ws_size,
                              hipStream_t stream)
{
    const float* X   = (const float*)d_in[0];
    const int*   e2  = (const int*)d_in[2];     // edges2 [2, E] int32
    const float* W1l = (const float*)d_in[5];
    const float* W1r = (const float*)d_in[6];
    const float* b1  = (const float*)d_in[7];
    const float* W2l = (const float*)d_in[8];
    const float* W2r = (const float*)d_in[9];
    const float* b2  = (const float*)d_in[10];
    const int* src = e2;
    const int* dst = e2 + N_EDGES;

    char* ws = (char*)d_ws;
    size_t off = 0;
    auto alloc = [&](size_t bytes) -> void* {
        void* p = ws + off;
        off += (bytes + 255) & ~(size_t)255;
        return p;
    };
    const size_t NB = (size_t)N_NODES * FEAT_CH * sizeof(float);  // 51.2 MB
    float* Yl = (float*)alloc(NB);
    float* Yr = (float*)alloc(NB);
    float* Zl = (float*)alloc((size_t)N_NODES * OUT_CH * sizeof(float));
    float* Zr = (float*)alloc((size_t)N_NODES * OUT_CH * sizeof(float));
    unsigned short* Wcat = (unsigned short*)alloc((size_t)256 * IN_CH * 2);
    int* cnt        = (int*)alloc((size_t)N_NODES * sizeof(int));
    int* cursor     = (int*)alloc((size_t)N_NODES * sizeof(int));
    int* rowptr     = (int*)alloc((size_t)(N_NODES + 1) * sizeof(int));
    int* bsum       = (int*)alloc((size_t)NCHUNK * sizeof(int));
    int* boff       = (int*)alloc((size_t)NCHUNK * sizeof(int));
    int* sorted_src = (int*)alloc((size_t)N_EDGES * sizeof(int));

    hipMemsetAsync(cnt,    0, (size_t)N_NODES * sizeof(int), stream);
    hipMemsetAsync(cursor, 0, (size_t)N_NODES * sizeof(int), stream);

    // --- CSR (counting sort by dst, parallel scan) ---
    hist_kernel<<<(N_EDGES + 255) / 256, 256, 0, stream>>>(dst, cnt);
    scan_p1<<<NCHUNK, 256, 0, stream>>>(cnt, rowptr, bsum);
    scan_p2<<<1, 256, 0, stream>>>(bsum, boff);
    scan_p3<<<NCHUNK, 256, 0, stream>>>(rowptr, boff);
    scatter_edges<<<(N_EDGES + 255) / 256, 256, 0, stream>>>(src, dst, rowptr, cursor,
                                                             sorted_src);

    // --- layer 1 GEMM (fused Yl/Yr) ---
    wt_kernel<<<(256 * IN_CH + 255) / 256, 256, 0, stream>>>(W1l, W1r, Wcat);
    gemm_fused<<<(N_NODES + 127) / 128, 256, 0, stream>>>(X, Wcat, Yl, Yr);

    // --- fused aggregation + combine + layer-2 projection ---
    fused_agg<<<(N_NODES * 64) / 256, 256, 0, stream>>>(Yl, Yr, rowptr, sorted_src,
                                                        b1, W2l, W2r, Zl, Zr);

    // --- layer-2 aggregation + output ---
    agg2_final<<<(N_NODES * 4 + 255) / 256, 256, 0, stream>>>(Zl, Zr, rowptr, sorted_src,
                                                              b2, (float*)d_out);
}